// Round 18
// baseline (456.761 us; speedup 1.0000x reference)
//
#include <hip/hip_runtime.h>
#include <hip/hip_bf16.h>

#define B_ 4
#define N_ 1569
#define IND 768
#define HEADS_ 12
#define HD_ 64
#define T0_ 8
#define H0_ 14
#define W0_ 14
#define M_ (B_*N_)          // 6276
#define MPAD 6400           // 50*128
#define QKVD (3*IND)        // 2304
#define NKT 25              // key/query tiles of 64
#define NPADK 1600          // padded key count
#define PBLK (3*B_*HEADS_*T0_)   // 1152 pool blocks
#define ABLK (B_*HEADS_*NKT)     // 1200 (bh,qt) units
#define ABLK2 (2*ABLK)           // 2400 split-K attn blocks

typedef __attribute__((ext_vector_type(8))) short short8v;
typedef __attribute__((ext_vector_type(8))) float float8;
typedef __attribute__((ext_vector_type(4))) float f32x4;

// async global->LDS 16B
#define GLOAD_LDS16(gp, lp) \
    __builtin_amdgcn_global_load_lds( \
        (const __attribute__((address_space(1))) void*)(gp), \
        (__attribute__((address_space(3))) void*)(lp), 16, 0, 0)

__device__ __forceinline__ short f2bfs(float f) {
    __hip_bfloat16 h = __float2bfloat16(f);
    return *reinterpret_cast<short*>(&h);
}
__device__ __forceinline__ float bfs2f(short s) {
    union { unsigned int i; float f; } x; x.i = ((unsigned int)(unsigned short)s) << 16; return x.f;
}
__device__ __forceinline__ unsigned int pk2bf(float a, float b) {
    return ((unsigned int)(unsigned short)f2bfs(b) << 16) | (unsigned short)f2bfs(a);
}
__device__ __forceinline__ float bfu2f_lo(unsigned int u) {
    union { unsigned int i; float f; } x; x.i = u << 16; return x.f;
}
__device__ __forceinline__ float bfu2f_hi(unsigned int u) {
    union { unsigned int i; float f; } x; x.i = u & 0xFFFF0000u; return x.f;
}

// ---- swizzled LDS helpers: 128B rows ----
__device__ __forceinline__ short8v lds_read8(const short* base, int row, int bir) {
    int byte = row * 128 + (bir ^ ((row & 7) << 4));
    return *reinterpret_cast<const short8v*>(reinterpret_cast<const char*>(base) + byte);
}
__device__ __forceinline__ void lds_writeP(short* base, int row, int bir, unsigned int lo, unsigned int hi) {
    int byte = row * 128 + (bir ^ ((row & 7) << 4));
    uint2 v; v.x = lo; v.y = hi;
    *reinterpret_cast<uint2*>(reinterpret_cast<char*>(base) + byte) = v;
}
// ---- swizzled LDS helpers: 256B rows (Q ext prologue tile) ----
__device__ __forceinline__ short8v lds_read8x(const short* base, int row, int bir) {
    int byte = row * 256 + (bir ^ ((row & 7) << 4));
    return *reinterpret_cast<const short8v*>(reinterpret_cast<const char*>(base) + byte);
}
__device__ __forceinline__ void lds_write8x(short* base, int row, int bir, short8v v) {
    int byte = row * 256 + (bir ^ ((row & 7) << 4));
    *reinterpret_cast<short8v*>(reinterpret_cast<char*>(base) + byte) = v;
}
__device__ __forceinline__ void lds_write1x(short* base, int row, int col, short v) {
    int byte = row * 256 + ((col * 2) ^ ((row & 7) << 4));
    *reinterpret_cast<short*>(reinterpret_cast<char*>(base) + byte) = v;
}

// ---------------- f32 -> bf16 row-wise convert with zero row padding ----------------
__global__ __launch_bounds__(256) void f32_to_bf16_rows(
        const float* __restrict__ src, short* __restrict__ dst, int rows, int cols) {
    const int r = blockIdx.x;
    const bool live = r < rows;
    for (int c = threadIdx.x; c < cols; c += 256) {
        float v = live ? src[(size_t)r * cols + c] : 0.f;
        dst[(size_t)r * cols + c] = f2bfs(v);
    }
}

// ---------------- W[K][N] f32 -> WT[N][K] bf16 ----------------
__global__ __launch_bounds__(256) void transpose_f32_bf16(
        const float* __restrict__ W, short* __restrict__ WT, int K, int N) {
    __shared__ float t[32][33];
    const int n0 = blockIdx.x * 32, k0 = blockIdx.y * 32;
    const int tx = threadIdx.x & 31, ty = threadIdx.x >> 5;
    #pragma unroll
    for (int p = 0; p < 4; p++)
        t[ty + 8 * p][tx] = W[(size_t)(k0 + ty + 8 * p) * N + n0 + tx];
    __syncthreads();
    #pragma unroll
    for (int p = 0; p < 4; p++)
        WT[(size_t)(n0 + ty + 8 * p) * K + k0 + tx] = f2bfs(t[tx][ty + 8 * p]);
}

// ---------------- rel-pos onehot table [NPADK][64] bf16, PRE-SWIZZLED cols ----------------
__global__ __launch_bounds__(64) void build_onehot(short* __restrict__ oneh) {
    const int kg = blockIdx.x;
    const int c = threadIdx.x;
    float v = 0.f;
    if (kg >= N_) {
        if (c == 36) v = -1e30f;
    } else if (kg >= 1) {
        int m = kg - 1;
        int tj = m / 196, rr = m - tj * 196;
        int hj = rr / 14, wj = rr - hj * 14;
        if (c == tj || c == 8 + hj || c == 22 + wj) v = 1.f;
    }
    oneh[(size_t)kg * 64 + (c ^ ((kg & 7) << 3))] = f2bfs(v);
}

// ---------------- MFMA GEMM: C[M,N] = A[Mpad,K](bf16) * BT[N,K]^T + bias ----------------
template<typename TOUT>
__global__ __launch_bounds__(256) void gemm_mfma(
        const short* __restrict__ A, const short* __restrict__ BT,
        const float* __restrict__ bias, TOUT* __restrict__ C,
        int M, int N, int K) {
    __shared__ __align__(16) short As[128 * 32];
    __shared__ __align__(16) short Bs[128 * 32];
    const int tid = threadIdx.x;
    const int lane = tid & 63;
    const int wid = tid >> 6;
    const int bm = blockIdx.y * 128;
    const int bn = blockIdx.x * 128;
    const int wr = (wid >> 1) * 64, wc = (wid & 1) * 64;
    const int larow = lane & 15, lak = (lane >> 4) * 8;
    const int srow = tid >> 2, sk = (tid & 3) * 8;

    f32x4 acc[4][4];
    #pragma unroll
    for (int m = 0; m < 4; m++)
        #pragma unroll
        for (int n = 0; n < 4; n++) acc[m][n] = (f32x4){0.f, 0.f, 0.f, 0.f};

    for (int kt = 0; kt < K; kt += 32) {
        __syncthreads();
        GLOAD_LDS16(A  + (size_t)(bm + srow) * K + kt + sk,       As + srow * 32 + sk);
        GLOAD_LDS16(A  + (size_t)(bm + 64 + srow) * K + kt + sk,  As + (64 + srow) * 32 + sk);
        GLOAD_LDS16(BT + (size_t)(bn + srow) * K + kt + sk,       Bs + srow * 32 + sk);
        GLOAD_LDS16(BT + (size_t)(bn + 64 + srow) * K + kt + sk,  Bs + (64 + srow) * 32 + sk);
        __syncthreads();

        short8v af[4], bfv[4];
        #pragma unroll
        for (int m = 0; m < 4; m++)
            af[m] = *(const short8v*)&As[(wr + m * 16 + larow) * 32 + lak];
        #pragma unroll
        for (int n = 0; n < 4; n++)
            bfv[n] = *(const short8v*)&Bs[(wc + n * 16 + larow) * 32 + lak];
        __builtin_amdgcn_s_setprio(1);
        #pragma unroll
        for (int m = 0; m < 4; m++)
            #pragma unroll
            for (int n = 0; n < 4; n++)
                acc[m][n] = __builtin_amdgcn_mfma_f32_16x16x32_bf16(af[m], bfv[n], acc[m][n], 0, 0, 0);
        __builtin_amdgcn_s_setprio(0);
    }

    const int crow = (lane >> 4) * 4;
    const int ccol = lane & 15;
    #pragma unroll
    for (int n = 0; n < 4; n++) {
        const int col = bn + wc + n * 16 + ccol;
        const float bv = bias[col];
        #pragma unroll
        for (int m = 0; m < 4; m++) {
            #pragma unroll
            for (int r2 = 0; r2 < 4; r2++) {
                const int row = bm + wr + m * 16 + crow + r2;
                if (row < M) {
                    float v = acc[m][n][r2] + bv;
                    if constexpr (sizeof(TOUT) == 2) C[(size_t)row * N + col] = f2bfs(v);
                    else                             C[(size_t)row * N + col] = v;
                }
            }
        }
    }
}

// ---------------- LDS-staged depthwise 3x3x3 conv pool + LayerNorm(64) ----------------
// K -> kswz [bh][NPADK][64] col ^ ((n&7)<<3); V -> vtb [bh][d][NPADK] per-64-tile col ^ ((d&7)<<3).
__global__ __launch_bounds__(256) void pool_ln(
        const short* __restrict__ qkvb,
        const float* __restrict__ kq, const float* __restrict__ kk,
        const float* __restrict__ kv,
        const float* __restrict__ nqw, const float* __restrict__ nqb,
        const float* __restrict__ nkw, const float* __restrict__ nkb,
        const float* __restrict__ nvw, const float* __restrict__ nvb,
        float* __restrict__ pqf, short* __restrict__ qbb,
        short* __restrict__ kswz, short* __restrict__ vtb) {
    __shared__ __align__(16) short sp[3 * 196 * 64];

    const int tid = threadIdx.x;
    const int lane = tid & 63;
    const int wid = tid >> 6;
    const int li = lane & 31;
    const int halfB = lane >> 5;

    int bid = (blockIdx.x & 7) * (PBLK / 8) + (blockIdx.x >> 3);
    const int t = bid & 7; bid >>= 3;
    const int head = bid % HEADS_; bid /= HEADS_;
    const int b = bid % B_;
    const int s = bid / B_;

    const float* kern = (s == 0) ? kq : ((s == 1) ? kk : kv);
    const float* lw = (s == 0) ? nqw : ((s == 1) ? nkw : nvw);
    const float* lb = (s == 0) ? nqb : ((s == 1) ? nkb : nvb);

    float kwA[27], kwB[27];
    #pragma unroll
    for (int i = 0; i < 27; i++) {
        kwA[i] = kern[(2 * li) * 27 + i];
        kwB[i] = kern[(2 * li + 1) * 27 + i];
    }
    const float lw0 = lw[2 * li], lw1 = lw[2 * li + 1];
    const float lb0 = lb[2 * li], lb1 = lb[2 * li + 1];
    const float oscale = (s == 0) ? 0.125f : 1.f;

    const int colbase = s * IND + head * HD_;

    for (int c = tid; c < 3 * 196 * 8; c += 256) {
        const int p = c / 1568, rem = c - p * 1568;
        const int t2 = t - 1 + p;
        short8v v = {0,0,0,0,0,0,0,0};
        if (t2 >= 0 && t2 < T0_) {
            const int node = rem >> 3, seg = rem & 7;
            v = *(const short8v*)(qkvb +
                (size_t)(b * N_ + 1 + t2 * 196 + node) * QKVD + colbase + seg * 8);
        }
        *(short8v*)&sp[c * 8] = v;
    }
    __syncthreads();

    const int bh = b * HEADS_ + head;
    const size_t qbase  = (size_t)bh * N_ * HD_ + 2 * li;
    const size_t kbase  = (size_t)bh * NPADK * HD_;
    const size_t vtbase = (size_t)bh * HD_ * NPADK;

    for (int pr = wid; pr < 98; pr += 4) {
        const int node = pr * 2 + halfB;
        const int hi = node / 14, wi = node - hi * 14;
        float y0 = 0.f, y1 = 0.f;
        #pragma unroll
        for (int kt2 = 0; kt2 < 3; kt2++)
            #pragma unroll
            for (int kh = 0; kh < 3; kh++)
                #pragma unroll
                for (int kw_ = 0; kw_ < 3; kw_++) {
                    const int h2 = hi + kh - 1, w2 = wi + kw_ - 1;
                    const bool ok = ((unsigned)h2 < 14u) && ((unsigned)w2 < 14u);
                    const int n2 = ok ? (h2 * 14 + w2) : 0;
                    const unsigned int u =
                        *(const unsigned int*)&sp[(kt2 * 196 + n2) * 64 + 2 * li];
                    const int ki = (kt2 * 3 + kh) * 3 + kw_;
                    const float w0 = ok ? kwA[ki] : 0.f;
                    const float w1 = ok ? kwB[ki] : 0.f;
                    y0 += bfu2f_lo(u) * w0;
                    y1 += bfu2f_hi(u) * w1;
                }
        float s1 = y0 + y1;
        #pragma unroll
        for (int o = 16; o > 0; o >>= 1) s1 += __shfl_xor(s1, o);
        const float mu = s1 * (1.f / 64.f);
        const float d0 = y0 - mu, d1 = y1 - mu;
        float s2 = d0 * d0 + d1 * d1;
        #pragma unroll
        for (int o = 16; o > 0; o >>= 1) s2 += __shfl_xor(s2, o);
        const float inv = rsqrtf(s2 * (1.f / 64.f) + 1e-5f);
        const float o0 = d0 * inv * lw0 + lb0;
        const float o1 = d1 * inv * lw1 + lb1;

        const int n = 1 + t * 196 + node;
        if (s == 2) {
            const int base64 = n & ~63, loc = n & 63;
            vtb[vtbase + (size_t)(2 * li) * NPADK + base64 + (loc ^ (((2 * li) & 7) << 3))]         = f2bfs(o0);
            vtb[vtbase + (size_t)(2 * li + 1) * NPADK + base64 + (loc ^ (((2 * li + 1) & 7) << 3))] = f2bfs(o1);
        } else if (s == 1) {
            const int cswz = (2 * li) ^ ((n & 7) << 3);
            *(unsigned int*)&kswz[kbase + (size_t)n * HD_ + cswz] = pk2bf(o0, o1);
        } else {
            const size_t idx = qbase + (size_t)n * HD_;
            *(unsigned int*)&qbb[idx] = pk2bf(o0 * oscale, o1 * oscale);
            float2 f2; f2.x = o0; f2.y = o1;
            *(float2*)&pqf[idx] = f2;
        }
    }

    if (t == 0 && wid == 0) {
        const unsigned int u =
            *(const unsigned int*)(qkvb + (size_t)(b * N_) * QKVD + colbase + 2 * li);
        const float y0 = bfu2f_lo(u), y1 = bfu2f_hi(u);
        float s1 = y0 + y1;
        #pragma unroll
        for (int o = 16; o > 0; o >>= 1) s1 += __shfl_xor(s1, o);
        const float mu = s1 * (1.f / 64.f);
        const float d0 = y0 - mu, d1 = y1 - mu;
        float s2 = d0 * d0 + d1 * d1;
        #pragma unroll
        for (int o = 16; o > 0; o >>= 1) s2 += __shfl_xor(s2, o);
        const float inv = rsqrtf(s2 * (1.f / 64.f) + 1e-5f);
        const float o0 = d0 * inv * lw0 + lb0;
        const float o1 = d1 * inv * lw1 + lb1;
        if (halfB == 0) {
            if (s == 2) {
                vtb[vtbase + (size_t)(2 * li) * NPADK + (((2 * li) & 7) << 3)]         = f2bfs(o0);
                vtb[vtbase + (size_t)(2 * li + 1) * NPADK + (((2 * li + 1) & 7) << 3)] = f2bfs(o1);
            } else if (s == 1) {
                *(unsigned int*)&kswz[kbase + 2 * li] = pk2bf(o0, o1);
            } else {
                *(unsigned int*)&qbb[qbase] = pk2bf(o0 * oscale, o1 * oscale);
                float2 f2; f2.x = o0; f2.y = o1;
                *(float2*)&pqf[qbase] = f2;
            }
        }
    }
}

// ---------------- split-K MFMA flash attention ----------------
// Block (half,bh,qt): key tiles [13*half, min(13*half+13,25)). Emits UNNORMALIZED
// partials: pOb bf16 [part][64 rows][64 d] (= sum e^{s-m} V) + pml f32 (m,l) per row.
__global__ __launch_bounds__(256) void attn_split(
        const short* __restrict__ qb, const short* __restrict__ kswz,
        const short* __restrict__ vtb, const short* __restrict__ oneh,
        const float* __restrict__ pqf,
        const float* __restrict__ rpt, const float* __restrict__ rph,
        const float* __restrict__ rpw,
        short* __restrict__ pOb, float* __restrict__ pml) {
    __shared__ __align__(16) short LDSbuf[16384];   // 32 KB

    short* Qse = LDSbuf;            // prologue only (16KB, 256B rows)
    short* Kk  = LDSbuf;            // 8KB, 128B rows
    short* Ke  = LDSbuf + 4096;     // 8KB, 128B rows
    short* VT  = LDSbuf + 8192;     // 8KB, 128B rows
    short* Ps  = LDSbuf + 12288;    // 8KB, 128B rows

    const int tid = threadIdx.x;
    const int lane = tid & 63;
    const int wid = tid >> 6;
    const int larow = lane & 15;
    const int lgrp = lane >> 4;

    int bid = (blockIdx.x & 7) * (ABLK2 / 8) + (blockIdx.x >> 3);
    const int half = bid / ABLK; bid -= half * ABLK;
    const int qt = bid % NKT; bid /= NKT;
    const int h = bid % HEADS_;
    const int b = bid / HEADS_;
    const int q0 = qt * 64;
    const int bh = b * HEADS_ + h;
    const size_t base = (size_t)bh * N_ * HD_;

    const int g32row = tid >> 3;
    const int g32col = (tid & 7) * 8;

    // ---- prologue: stage Qext ----
    {
        const int row = tid >> 2, seg = tid & 3;
        const int qi = q0 + row;
        short8v v0 = {0,0,0,0,0,0,0,0}, v1 = v0, z = v0;
        if (qi < N_) {
            const short8v* g = (const short8v*)(qb + base + (size_t)qi * HD_ + seg * 16);
            v0 = g[0]; v1 = g[1];
        }
        lds_write8x(Qse, row, seg * 32, v0);
        lds_write8x(Qse, row, seg * 32 + 16, v1);
        lds_write8x(Qse, row, 128 + seg * 32, z);
        lds_write8x(Qse, row, 128 + seg * 32 + 16, z);
    }
    __syncthreads();

    // ---- rel-pos dots -> Qext cols 64..99; mask col 100 = 1.0 ----
    #pragma unroll
    for (int it = 0; it < 9; it++) {
        int flat = it * 256 + tid;
        int row = flat / 36, idx = flat - row * 36;
        int qi = q0 + row;
        bool valid = (qi >= 1 && qi < N_);
        int m = valid ? (qi - 1) : 0;
        int ti = m / 196, rr2 = m - ti * 196;
        int hi = rr2 / 14, wi = rr2 - hi * 14;
        const float* tab;
        if (idx < 8)       tab = rpt + (size_t)(ti - idx + 7) * HD_;
        else if (idx < 22) tab = rph + (size_t)(hi - (idx - 8) + 13) * HD_;
        else               tab = rpw + (size_t)(wi - (idx - 22) + 13) * HD_;
        float acc = 0.f;
        if (valid) {
            const float4* qp = (const float4*)(pqf + base + (size_t)qi * HD_);
            const float4* tp = (const float4*)tab;
            #pragma unroll 4
            for (int dd = 0; dd < 16; dd++) {
                float4 a = qp[dd], t = tp[dd];
                acc += a.x * t.x + a.y * t.y + a.z * t.z + a.w * t.w;
            }
        }
        lds_write1x(Qse, row, 64 + idx, f2bfs(acc));
    }
    if (tid < 64) lds_write1x(Qse, tid, 100, (short)0x3F80);   // 1.0 bf16
    __syncthreads();

    // ---- hoist Q' B-frags ----
    short8v bq[4];
    #pragma unroll
    for (int ks = 0; ks < 4; ks++)
        bq[ks] = lds_read8x(Qse, wid * 16 + larow, ks * 64 + lgrp * 16);

    float m_ = -1e30f, l_ = 0.f;
    f32x4 O4[4];
    #pragma unroll
    for (int nf = 0; nf < 4; nf++) O4[nf] = (f32x4){0.f, 0.f, 0.f, 0.f};

    const int prow = wid * 16 + larow;
    const int kt0 = half * 13;
    const int ktEnd = (kt0 + 13 < NKT) ? kt0 + 13 : NKT;

    for (int kt = kt0; kt < ktEnd; kt++) {
        __syncthreads();
        {
            const int kb0 = kt * 64;
            #pragma unroll
            for (int p = 0; p < 2; p++) {
                const int row = p * 32 + g32row;
                GLOAD_LDS16(kswz + ((size_t)bh * NPADK + kb0 + row) * HD_ + g32col,
                            Kk + p * 2048 + tid * 8);
                GLOAD_LDS16(oneh + (size_t)(kb0 + row) * 64 + g32col,
                            Ke + p * 2048 + tid * 8);
                GLOAD_LDS16(vtb + ((size_t)bh * HD_ + row) * NPADK + kb0 + g32col,
                            VT + p * 2048 + tid * 8);
            }
        }
        __syncthreads();

        f32x4 s4[4];
        #pragma unroll
        for (int nf = 0; nf < 4; nf++) {
            short8v ak[4];
            ak[0] = lds_read8(Kk, nf * 16 + larow, lgrp * 16);
            ak[1] = lds_read8(Kk, nf * 16 + larow, 64 + lgrp * 16);
            ak[2] = lds_read8(Ke, nf * 16 + larow, lgrp * 16);
            ak[3] = lds_read8(Ke, nf * 16 + larow, 64 + lgrp * 16);
            f32x4 acc = (f32x4){0.f, 0.f, 0.f, 0.f};
            #pragma unroll
            for (int ks = 0; ks < 4; ks++)
                acc = __builtin_amdgcn_mfma_f32_16x16x32_bf16(ak[ks], bq[ks], acc, 0, 0, 0);
            s4[nf] = acc;
        }

        float rm = -1e30f;
        #pragma unroll
        for (int nf = 0; nf < 4; nf++)
            #pragma unroll
            for (int r = 0; r < 4; r++) rm = fmaxf(rm, s4[nf][r]);
        rm = fmaxf(rm, __shfl_xor(rm, 16));
        rm = fmaxf(rm, __shfl_xor(rm, 32));
        const bool noresc = __all(rm <= m_ + 8.f);
        float fac = 1.f;
        if (!noresc) {
            float mn = fmaxf(m_, rm);
            fac = __expf(m_ - mn);
            m_ = mn;
        }
        float p[4][4];
        float ps = 0.f;
        #pragma unroll
        for (int nf = 0; nf < 4; nf++)
            #pragma unroll
            for (int r = 0; r < 4; r++) {
                float e = __expf(s4[nf][r] - m_);
                p[nf][r] = e; ps += e;
            }
        ps += __shfl_xor(ps, 16);
        ps += __shfl_xor(ps, 32);
        l_ = l_ * fac + ps;

        #pragma unroll
        for (int nf = 0; nf < 4; nf++)
            lds_writeP(Ps, prow, nf * 32 + lgrp * 8,
                       pk2bf(p[nf][0], p[nf][1]), pk2bf(p[nf][2], p[nf][3]));

        if (!noresc) {
            float facr[4];
            #pragma unroll
            for (int r = 0; r < 4; r++) facr[r] = __shfl(fac, lgrp * 4 + r);
            #pragma unroll
            for (int nf = 0; nf < 4; nf++)
                #pragma unroll
                for (int r = 0; r < 4; r++) O4[nf][r] *= facr[r];
        }

        short8v ap[2];
        ap[0] = lds_read8(Ps, prow, lgrp * 16);
        ap[1] = lds_read8(Ps, prow, 64 + lgrp * 16);
        #pragma unroll
        for (int nf = 0; nf < 4; nf++) {
            #pragma unroll
            for (int ks = 0; ks < 2; ks++) {
                short8v bv2 = lds_read8(VT, nf * 16 + larow, ks * 64 + lgrp * 16);
                O4[nf] = __builtin_amdgcn_mfma_f32_16x16x32_bf16(ap[ks], bv2, O4[nf], 0, 0, 0);
            }
        }
    }

    // ---- emit partials (unnormalized O in bf16; per-row m,l in f32) ----
    const size_t pbase = (size_t)(half * B_ * HEADS_ + bh) * NKT + qt;
    short* po = pOb + pbase * 4096;
    #pragma unroll
    for (int nf = 0; nf < 4; nf++) {
        const int d = nf * 16 + larow;
        #pragma unroll
        for (int r = 0; r < 4; r++) {
            const int rowL = wid * 16 + lgrp * 4 + r;
            po[rowL * 64 + d] = f2bfs(O4[nf][r]);
        }
    }
    if (lgrp == 0) {
        float2 v; v.x = m_; v.y = l_;
        *(float2*)&pml[(pbase * 64 + prow) * 2] = v;
    }
}

// ---------------- split-K merge: combine 2 halves, /l, +residual, store bf16 ----------------
__global__ __launch_bounds__(256) void attn_merge(
        const short* __restrict__ pOb, const float* __restrict__ pml,
        const float* __restrict__ pqf, short* __restrict__ aoutbf) {
    int bid = blockIdx.x;              // 0..1199 (bh, qt)
    const int qt = bid % NKT; bid /= NKT;
    const int h = bid % HEADS_;
    const int b = bid / HEADS_;
    const int bh = b * HEADS_ + h;
    const int row = threadIdx.x >> 2;
    const int dc = (threadIdx.x & 3) * 16;
    const int qi = qt * 64 + row;
    if (qi >= N_) return;

    const size_t p0 = (size_t)bh * NKT + qt;
    const size_t p1 = (size_t)(B_ * HEADS_ + bh) * NKT + qt;
    const float2 ml0 = *(const float2*)&pml[(p0 * 64 + row) * 2];
    const float2 ml1 = *(const float2*)&pml[(p1 * 64 + row) * 2];
    const float m = fmaxf(ml0.x, ml1.x);
    const float w0 = __expf(ml0.x - m), w1 = __expf(ml1.x - m);
    const float inv = 1.f / (ml0.y * w0 + ml1.y * w1);

    const short8v* o0p = (const short8v*)&pOb[p0 * 4096 + row * 64 + dc];
    const short8v* o1p = (const short8v*)&pOb[p1 * 4096 + row * 64 + dc];
    short8v o0a = o0p[0], o0b = o0p[1], o1a = o1p[0], o1b = o1p[1];

    float rv[16];
    #pragma unroll
    for (int j = 0; j < 16; j++) rv[j] = 0.f;
    if (qi > 0) {
        const float4* r4 = (const float4*)(pqf + ((size_t)bh * N_ + qi) * HD_ + dc);
        #pragma unroll
        for (int j = 0; j < 4; j++) {
            float4 v = r4[j];
            rv[4 * j] = v.x; rv[4 * j + 1] = v.y; rv[4 * j + 2] = v.z; rv[4 * j + 3] = v.w;
        }
    }

    short tmp[16];
    #pragma unroll
    for (int j = 0; j < 16; j++) {
        float v0 = bfs2f(j < 8 ? o0a[j] : o0b[j - 8]);
        float v1 = bfs2f(j < 8 ? o1a[j] : o1b[j - 8]);
        tmp[j] = f2bfs((v0 * w0 + v1 * w1) * inv + rv[j]);
    }
    short8v* dst = (short8v*)&aoutbf[(size_t)(b * N_ + qi) * (HEADS_ * HD_) + h * HD_ + dc];
    dst[0] = *(short8v*)&tmp[0];
    dst[1] = *(short8v*)&tmp[8];
}

extern "C" void kernel_launch(void* const* d_in, const int* in_sizes, int n_in,
                              void* d_out, int out_size, void* d_ws, size_t ws_size,
                              hipStream_t stream) {
    const float* x    = (const float*)d_in[0];
    const float* Wqkv = (const float*)d_in[1];
    const float* bqkv = (const float*)d_in[2];
    const float* kq   = (const float*)d_in[3];
    const float* kk   = (const float*)d_in[4];
    const float* kv   = (const float*)d_in[5];
    const float* nqw  = (const float*)d_in[6];
    const float* nqb  = (const float*)d_in[7];
    const float* nkw  = (const float*)d_in[8];
    const float* nkb  = (const float*)d_in[9];
    const float* nvw  = (const float*)d_in[10];
    const float* nvb  = (const float*)d_in[11];
    const float* rpt  = (const float*)d_in[12];
    const float* rph  = (const float*)d_in[13];
    const float* rpw  = (const float*)d_in[14];
    const float* Wproj= (const float*)d_in[15];
    const float* bproj= (const float*)d_in[16];
    float* out = (float*)d_out;

    const size_t qkv_elems  = (size_t)M_ * QKVD;
    const size_t pool_elems = (size_t)B_ * HEADS_ * N_ * HD_;
    const size_t kswz_elems = (size_t)B_ * HEADS_ * NPADK * HD_;
    short* qkvb = (short*)d_ws;                    // 28.9 MB
    float* pqf  = (float*)(qkvb + qkv_elems);      // 19.3 MB
    short* qbb  = (short*)(pqf + pool_elems);      // 9.6 MB
    short* kswz = qbb + pool_elems;                // 9.8 MB
    short* abuf = kswz + kswz_elems;               // 9.8 MB
    short* w1t  = abuf + (size_t)MPAD * IND;       // 3.5 MB
    short* vtb  = w1t + (size_t)QKVD * IND;        // 9.8 MB
    short* oneh = vtb + (size_t)B_ * HEADS_ * HD_ * NPADK;  // 0.2 MB
    short* pOb  = oneh + (size_t)NPADK * 64;       // 2*48*25*4096 bf16 = 39.3 MB
    float* pml  = (float*)(pOb + (size_t)2 * B_ * HEADS_ * NKT * 4096);  // 1.2 MB
                                                   // total ~132 MB

    f32_to_bf16_rows<<<MPAD, 256, 0, stream>>>(x, abuf, M_, IND);
    transpose_f32_bf16<<<dim3(QKVD / 32, IND / 32), 256, 0, stream>>>(Wqkv, w1t, IND, QKVD);
    build_onehot<<<NPADK, 64, 0, stream>>>(oneh);

    gemm_mfma<short><<<dim3(QKVD / 128, MPAD / 128), 256, 0, stream>>>(abuf, w1t, bqkv, qkvb, M_, QKVD, IND);

    pool_ln<<<PBLK, 256, 0, stream>>>(qkvb, kq, kk, kv,
        nqw, nqb, nkw, nkb, nvw, nvb, pqf, qbb, kswz, vtb);

    attn_split<<<ABLK2, 256, 0, stream>>>(qbb, kswz, vtb, oneh, pqf, rpt, rph, rpw, pOb, pml);
    attn_merge<<<ABLK, 256, 0, stream>>>(pOb, pml, pqf, abuf);

    transpose_f32_bf16<<<dim3(IND / 32, IND / 32), 256, 0, stream>>>(Wproj, w1t, IND, IND);
    gemm_mfma<float><<<dim3(IND / 128, MPAD / 128), 256, 0, stream>>>(abuf, w1t, bproj, out, M_, IND, IND);
}

// Round 19
// 340.636 us; speedup vs baseline: 1.3409x; 1.3409x over previous
//
#include <hip/hip_runtime.h>
#include <hip/hip_bf16.h>

#define B_ 4
#define N_ 1569
#define IND 768
#define HEADS_ 12
#define HD_ 64
#define T0_ 8
#define H0_ 14
#define W0_ 14
#define M_ (B_*N_)          // 6276
#define MPAD 6400           // 50*128
#define QKVD (3*IND)        // 2304
#define NKT 25              // key/query tiles of 64
#define NPADK 1600          // padded key count
#define PBLK (3*B_*HEADS_*T0_)   // 1152 pool blocks
#define ABLK (B_*HEADS_*NKT)     // 1200 attn blocks

typedef __attribute__((ext_vector_type(8))) short short8v;
typedef __attribute__((ext_vector_type(8))) float float8;
typedef __attribute__((ext_vector_type(4))) float f32x4;

// async global->LDS 16B
#define GLOAD_LDS16(gp, lp) \
    __builtin_amdgcn_global_load_lds( \
        (const __attribute__((address_space(1))) void*)(gp), \
        (__attribute__((address_space(3))) void*)(lp), 16, 0, 0)

__device__ __forceinline__ short f2bfs(float f) {
    __hip_bfloat16 h = __float2bfloat16(f);
    return *reinterpret_cast<short*>(&h);
}
__device__ __forceinline__ unsigned int pk2bf(float a, float b) {
    return ((unsigned int)(unsigned short)f2bfs(b) << 16) | (unsigned short)f2bfs(a);
}
__device__ __forceinline__ float bfu2f_lo(unsigned int u) {
    union { unsigned int i; float f; } x; x.i = u << 16; return x.f;
}
__device__ __forceinline__ float bfu2f_hi(unsigned int u) {
    union { unsigned int i; float f; } x; x.i = u & 0xFFFF0000u; return x.f;
}

// ---- swizzled LDS helpers: 128B rows ----
__device__ __forceinline__ short8v lds_read8(const short* base, int row, int bir) {
    int byte = row * 128 + (bir ^ ((row & 7) << 4));
    return *reinterpret_cast<const short8v*>(reinterpret_cast<const char*>(base) + byte);
}
__device__ __forceinline__ void lds_writeP(short* base, int row, int bir, unsigned int lo, unsigned int hi) {
    int byte = row * 128 + (bir ^ ((row & 7) << 4));
    uint2 v; v.x = lo; v.y = hi;
    *reinterpret_cast<uint2*>(reinterpret_cast<char*>(base) + byte) = v;
}
// ---- swizzled LDS helpers: 256B rows (Q ext prologue tile) ----
__device__ __forceinline__ short8v lds_read8x(const short* base, int row, int bir) {
    int byte = row * 256 + (bir ^ ((row & 7) << 4));
    return *reinterpret_cast<const short8v*>(reinterpret_cast<const char*>(base) + byte);
}
__device__ __forceinline__ void lds_write8x(short* base, int row, int bir, short8v v) {
    int byte = row * 256 + (bir ^ ((row & 7) << 4));
    *reinterpret_cast<short8v*>(reinterpret_cast<char*>(base) + byte) = v;
}
__device__ __forceinline__ void lds_write1x(short* base, int row, int col, short v) {
    int byte = row * 256 + ((col * 2) ^ ((row & 7) << 4));
    *reinterpret_cast<short*>(reinterpret_cast<char*>(base) + byte) = v;
}

// ---------------- f32 -> bf16 row-wise convert with zero row padding ----------------
__global__ __launch_bounds__(256) void f32_to_bf16_rows(
        const float* __restrict__ src, short* __restrict__ dst, int rows, int cols) {
    const int r = blockIdx.x;
    const bool live = r < rows;
    for (int c = threadIdx.x; c < cols; c += 256) {
        float v = live ? src[(size_t)r * cols + c] : 0.f;
        dst[(size_t)r * cols + c] = f2bfs(v);
    }
}

// ---------------- W[K][N] f32 -> WT[N][K] bf16 ----------------
__global__ __launch_bounds__(256) void transpose_f32_bf16(
        const float* __restrict__ W, short* __restrict__ WT, int K, int N) {
    __shared__ float t[32][33];
    const int n0 = blockIdx.x * 32, k0 = blockIdx.y * 32;
    const int tx = threadIdx.x & 31, ty = threadIdx.x >> 5;
    #pragma unroll
    for (int p = 0; p < 4; p++)
        t[ty + 8 * p][tx] = W[(size_t)(k0 + ty + 8 * p) * N + n0 + tx];
    __syncthreads();
    #pragma unroll
    for (int p = 0; p < 4; p++)
        WT[(size_t)(n0 + ty + 8 * p) * K + k0 + tx] = f2bfs(t[tx][ty + 8 * p]);
}

// ---------------- rel-pos onehot table [NPADK][64] bf16, PRE-SWIZZLED cols ----------------
__global__ __launch_bounds__(64) void build_onehot(short* __restrict__ oneh) {
    const int kg = blockIdx.x;
    const int c = threadIdx.x;
    float v = 0.f;
    if (kg >= N_) {
        if (c == 36) v = -1e30f;
    } else if (kg >= 1) {
        int m = kg - 1;
        int tj = m / 196, rr = m - tj * 196;
        int hj = rr / 14, wj = rr - hj * 14;
        if (c == tj || c == 8 + hj || c == 22 + wj) v = 1.f;
    }
    oneh[(size_t)kg * 64 + (c ^ ((kg & 7) << 3))] = f2bfs(v);
}

// ---------------- precompute rel-pos dots: relq[bh][NPADK rows][36] bf16 ----------------
// block = (bh, qt); 256 threads = 64 rows x 4 parts (16 dims each).
// q held in registers; tables are 17.7KB L1-hot; part-reduce via shfl_xor 1,2.
__global__ __launch_bounds__(256) void build_relq(
        const float* __restrict__ pqf,
        const float* __restrict__ rpt, const float* __restrict__ rph,
        const float* __restrict__ rpw, short* __restrict__ relq) {
    int bid = blockIdx.x;                  // 48*25
    const int qt = bid % NKT; bid /= NKT;
    const int bh = bid;
    const int row = threadIdx.x >> 2, part = threadIdx.x & 3;
    const int qi = qt * 64 + row;
    const bool valid = (qi >= 1 && qi < N_);
    const int m = valid ? (qi - 1) : 0;
    const int ti = m / 196, rr = m - ti * 196;
    const int hi = rr / 14, wi = rr - hi * 14;

    float4 qv[4];
    if (valid) {
        const float4* qp = (const float4*)(pqf + ((size_t)bh * N_ + qi) * HD_ + part * 16);
        qv[0] = qp[0]; qv[1] = qp[1]; qv[2] = qp[2]; qv[3] = qp[3];
    } else {
        #pragma unroll
        for (int j = 0; j < 4; j++) qv[j] = make_float4(0.f, 0.f, 0.f, 0.f);
    }

    short* dst = relq + ((size_t)bh * NPADK + qt * 64 + row) * 36;
    #pragma unroll 4
    for (int idx = 0; idx < 36; idx++) {
        const float* tab;
        if (idx < 8)       tab = rpt + (size_t)(ti - idx + 7) * HD_;
        else if (idx < 22) tab = rph + (size_t)(hi - (idx - 8) + 13) * HD_;
        else               tab = rpw + (size_t)(wi - (idx - 22) + 13) * HD_;
        const float4* tp = (const float4*)(tab + part * 16);
        float acc = 0.f;
        #pragma unroll
        for (int j = 0; j < 4; j++) {
            float4 t = tp[j];
            acc += qv[j].x * t.x + qv[j].y * t.y + qv[j].z * t.z + qv[j].w * t.w;
        }
        acc += __shfl_xor(acc, 1);
        acc += __shfl_xor(acc, 2);
        if (part == 0) dst[idx] = valid ? f2bfs(acc) : (short)0;
    }
}

// ---------------- MFMA GEMM: C[M,N] = A[Mpad,K](bf16) * BT[N,K]^T + bias ----------------
template<typename TOUT>
__global__ __launch_bounds__(256) void gemm_mfma(
        const short* __restrict__ A, const short* __restrict__ BT,
        const float* __restrict__ bias, TOUT* __restrict__ C,
        int M, int N, int K) {
    __shared__ __align__(16) short As[128 * 32];
    __shared__ __align__(16) short Bs[128 * 32];
    const int tid = threadIdx.x;
    const int lane = tid & 63;
    const int wid = tid >> 6;
    const int bm = blockIdx.y * 128;
    const int bn = blockIdx.x * 128;
    const int wr = (wid >> 1) * 64, wc = (wid & 1) * 64;
    const int larow = lane & 15, lak = (lane >> 4) * 8;
    const int srow = tid >> 2, sk = (tid & 3) * 8;

    f32x4 acc[4][4];
    #pragma unroll
    for (int m = 0; m < 4; m++)
        #pragma unroll
        for (int n = 0; n < 4; n++) acc[m][n] = (f32x4){0.f, 0.f, 0.f, 0.f};

    for (int kt = 0; kt < K; kt += 32) {
        __syncthreads();
        GLOAD_LDS16(A  + (size_t)(bm + srow) * K + kt + sk,       As + srow * 32 + sk);
        GLOAD_LDS16(A  + (size_t)(bm + 64 + srow) * K + kt + sk,  As + (64 + srow) * 32 + sk);
        GLOAD_LDS16(BT + (size_t)(bn + srow) * K + kt + sk,       Bs + srow * 32 + sk);
        GLOAD_LDS16(BT + (size_t)(bn + 64 + srow) * K + kt + sk,  Bs + (64 + srow) * 32 + sk);
        __syncthreads();

        short8v af[4], bfv[4];
        #pragma unroll
        for (int m = 0; m < 4; m++)
            af[m] = *(const short8v*)&As[(wr + m * 16 + larow) * 32 + lak];
        #pragma unroll
        for (int n = 0; n < 4; n++)
            bfv[n] = *(const short8v*)&Bs[(wc + n * 16 + larow) * 32 + lak];
        __builtin_amdgcn_s_setprio(1);
        #pragma unroll
        for (int m = 0; m < 4; m++)
            #pragma unroll
            for (int n = 0; n < 4; n++)
                acc[m][n] = __builtin_amdgcn_mfma_f32_16x16x32_bf16(af[m], bfv[n], acc[m][n], 0, 0, 0);
        __builtin_amdgcn_s_setprio(0);
    }

    const int crow = (lane >> 4) * 4;
    const int ccol = lane & 15;
    #pragma unroll
    for (int n = 0; n < 4; n++) {
        const int col = bn + wc + n * 16 + ccol;
        const float bv = bias[col];
        #pragma unroll
        for (int m = 0; m < 4; m++) {
            #pragma unroll
            for (int r2 = 0; r2 < 4; r2++) {
                const int row = bm + wr + m * 16 + crow + r2;
                if (row < M) {
                    float v = acc[m][n][r2] + bv;
                    if constexpr (sizeof(TOUT) == 2) C[(size_t)row * N + col] = f2bfs(v);
                    else                             C[(size_t)row * N + col] = v;
                }
            }
        }
    }
}

// ---------------- LDS-staged depthwise 3x3x3 conv pool + LayerNorm(64) ----------------
// K -> kswz [bh][NPADK][64] col ^ ((n&7)<<3); V -> vtb [bh][d][NPADK] per-64-tile col ^ ((d&7)<<3).
__global__ __launch_bounds__(256) void pool_ln(
        const short* __restrict__ qkvb,
        const float* __restrict__ kq, const float* __restrict__ kk,
        const float* __restrict__ kv,
        const float* __restrict__ nqw, const float* __restrict__ nqb,
        const float* __restrict__ nkw, const float* __restrict__ nkb,
        const float* __restrict__ nvw, const float* __restrict__ nvb,
        float* __restrict__ pqf, short* __restrict__ qbb,
        short* __restrict__ kswz, short* __restrict__ vtb) {
    __shared__ __align__(16) short sp[3 * 196 * 64];

    const int tid = threadIdx.x;
    const int lane = tid & 63;
    const int wid = tid >> 6;
    const int li = lane & 31;
    const int halfB = lane >> 5;

    int bid = (blockIdx.x & 7) * (PBLK / 8) + (blockIdx.x >> 3);
    const int t = bid & 7; bid >>= 3;
    const int head = bid % HEADS_; bid /= HEADS_;
    const int b = bid % B_;
    const int s = bid / B_;

    const float* kern = (s == 0) ? kq : ((s == 1) ? kk : kv);
    const float* lw = (s == 0) ? nqw : ((s == 1) ? nkw : nvw);
    const float* lb = (s == 0) ? nqb : ((s == 1) ? nkb : nvb);

    float kwA[27], kwB[27];
    #pragma unroll
    for (int i = 0; i < 27; i++) {
        kwA[i] = kern[(2 * li) * 27 + i];
        kwB[i] = kern[(2 * li + 1) * 27 + i];
    }
    const float lw0 = lw[2 * li], lw1 = lw[2 * li + 1];
    const float lb0 = lb[2 * li], lb1 = lb[2 * li + 1];
    const float oscale = (s == 0) ? 0.125f : 1.f;

    const int colbase = s * IND + head * HD_;

    for (int c = tid; c < 3 * 196 * 8; c += 256) {
        const int p = c / 1568, rem = c - p * 1568;
        const int t2 = t - 1 + p;
        short8v v = {0,0,0,0,0,0,0,0};
        if (t2 >= 0 && t2 < T0_) {
            const int node = rem >> 3, seg = rem & 7;
            v = *(const short8v*)(qkvb +
                (size_t)(b * N_ + 1 + t2 * 196 + node) * QKVD + colbase + seg * 8);
        }
        *(short8v*)&sp[c * 8] = v;
    }
    __syncthreads();

    const int bh = b * HEADS_ + head;
    const size_t qbase  = (size_t)bh * N_ * HD_ + 2 * li;
    const size_t kbase  = (size_t)bh * NPADK * HD_;
    const size_t vtbase = (size_t)bh * HD_ * NPADK;

    for (int pr = wid; pr < 98; pr += 4) {
        const int node = pr * 2 + halfB;
        const int hi = node / 14, wi = node - hi * 14;
        float y0 = 0.f, y1 = 0.f;
        #pragma unroll
        for (int kt2 = 0; kt2 < 3; kt2++)
            #pragma unroll
            for (int kh = 0; kh < 3; kh++)
                #pragma unroll
                for (int kw_ = 0; kw_ < 3; kw_++) {
                    const int h2 = hi + kh - 1, w2 = wi + kw_ - 1;
                    const bool ok = ((unsigned)h2 < 14u) && ((unsigned)w2 < 14u);
                    const int n2 = ok ? (h2 * 14 + w2) : 0;
                    const unsigned int u =
                        *(const unsigned int*)&sp[(kt2 * 196 + n2) * 64 + 2 * li];
                    const int ki = (kt2 * 3 + kh) * 3 + kw_;
                    const float w0 = ok ? kwA[ki] : 0.f;
                    const float w1 = ok ? kwB[ki] : 0.f;
                    y0 += bfu2f_lo(u) * w0;
                    y1 += bfu2f_hi(u) * w1;
                }
        float s1 = y0 + y1;
        #pragma unroll
        for (int o = 16; o > 0; o >>= 1) s1 += __shfl_xor(s1, o);
        const float mu = s1 * (1.f / 64.f);
        const float d0 = y0 - mu, d1 = y1 - mu;
        float s2 = d0 * d0 + d1 * d1;
        #pragma unroll
        for (int o = 16; o > 0; o >>= 1) s2 += __shfl_xor(s2, o);
        const float inv = rsqrtf(s2 * (1.f / 64.f) + 1e-5f);
        const float o0 = d0 * inv * lw0 + lb0;
        const float o1 = d1 * inv * lw1 + lb1;

        const int n = 1 + t * 196 + node;
        if (s == 2) {
            const int base64 = n & ~63, loc = n & 63;
            vtb[vtbase + (size_t)(2 * li) * NPADK + base64 + (loc ^ (((2 * li) & 7) << 3))]         = f2bfs(o0);
            vtb[vtbase + (size_t)(2 * li + 1) * NPADK + base64 + (loc ^ (((2 * li + 1) & 7) << 3))] = f2bfs(o1);
        } else if (s == 1) {
            const int cswz = (2 * li) ^ ((n & 7) << 3);
            *(unsigned int*)&kswz[kbase + (size_t)n * HD_ + cswz] = pk2bf(o0, o1);
        } else {
            const size_t idx = qbase + (size_t)n * HD_;
            *(unsigned int*)&qbb[idx] = pk2bf(o0 * oscale, o1 * oscale);
            float2 f2; f2.x = o0; f2.y = o1;
            *(float2*)&pqf[idx] = f2;
        }
    }

    if (t == 0 && wid == 0) {
        const unsigned int u =
            *(const unsigned int*)(qkvb + (size_t)(b * N_) * QKVD + colbase + 2 * li);
        const float y0 = bfu2f_lo(u), y1 = bfu2f_hi(u);
        float s1 = y0 + y1;
        #pragma unroll
        for (int o = 16; o > 0; o >>= 1) s1 += __shfl_xor(s1, o);
        const float mu = s1 * (1.f / 64.f);
        const float d0 = y0 - mu, d1 = y1 - mu;
        float s2 = d0 * d0 + d1 * d1;
        #pragma unroll
        for (int o = 16; o > 0; o >>= 1) s2 += __shfl_xor(s2, o);
        const float inv = rsqrtf(s2 * (1.f / 64.f) + 1e-5f);
        const float o0 = d0 * inv * lw0 + lb0;
        const float o1 = d1 * inv * lw1 + lb1;
        if (halfB == 0) {
            if (s == 2) {
                vtb[vtbase + (size_t)(2 * li) * NPADK + (((2 * li) & 7) << 3)]         = f2bfs(o0);
                vtb[vtbase + (size_t)(2 * li + 1) * NPADK + (((2 * li + 1) & 7) << 3)] = f2bfs(o1);
            } else if (s == 1) {
                *(unsigned int*)&kswz[kbase + 2 * li] = pk2bf(o0, o1);
            } else {
                *(unsigned int*)&qbb[qbase] = pk2bf(o0 * oscale, o1 * oscale);
                float2 f2; f2.x = o0; f2.y = o1;
                *(float2*)&pqf[qbase] = f2;
            }
        }
    }
}

// ---------------- MFMA flash attention: precomputed relq; gload_lds staging ----------------
// LDS 32KB: Kk[64][128B] | Ke[64][128B] | VT[64][128B] | Ps[64][128B]; Qse(16KB) overlays Kk+Ke.
__global__ __launch_bounds__(256) void attn_mfma(
        const short* __restrict__ qb, const short* __restrict__ kswz,
        const short* __restrict__ vtb, const short* __restrict__ oneh,
        const short* __restrict__ relq, const float* __restrict__ pqf,
        short* __restrict__ aoutbf) {
    __shared__ __align__(16) short LDSbuf[16384];   // 32 KB

    short* Qse = LDSbuf;            // prologue only (16KB, 256B rows)
    short* Kk  = LDSbuf;            // 8KB, 128B rows
    short* Ke  = LDSbuf + 4096;     // 8KB, 128B rows
    short* VT  = LDSbuf + 8192;     // 8KB, 128B rows
    short* Ps  = LDSbuf + 12288;    // 8KB, 128B rows

    const int tid = threadIdx.x;
    const int lane = tid & 63;
    const int wid = tid >> 6;
    const int larow = lane & 15;
    const int lgrp = lane >> 4;

    int bid = (blockIdx.x & 7) * (ABLK / 8) + (blockIdx.x >> 3);
    const int qt = bid % NKT; bid /= NKT;
    const int h = bid % HEADS_;
    const int b = bid / HEADS_;
    const int q0 = qt * 64;
    const int bh = b * HEADS_ + h;
    const size_t base = (size_t)bh * N_ * HD_;

    const int g32row = tid >> 3;
    const int g32col = (tid & 7) * 8;

    // ---- prologue: stage Qext (zero-padded; ext half zeroed) ----
    {
        const int row = tid >> 2, seg = tid & 3;
        const int qi = q0 + row;
        short8v v0 = {0,0,0,0,0,0,0,0}, v1 = v0, z = v0;
        if (qi < N_) {
            const short8v* g = (const short8v*)(qb + base + (size_t)qi * HD_ + seg * 16);
            v0 = g[0]; v1 = g[1];
        }
        lds_write8x(Qse, row, seg * 32, v0);
        lds_write8x(Qse, row, seg * 32 + 16, v1);
        lds_write8x(Qse, row, 128 + seg * 32, z);
        lds_write8x(Qse, row, 128 + seg * 32 + 16, z);
    }
    __syncthreads();

    // ---- copy precomputed rel dots -> Qext cols 64..99; mask col 100 = 1.0 ----
    #pragma unroll
    for (int it = 0; it < 9; it++) {           // 9*256 = 2304 = 64*36
        int flat = it * 256 + tid;
        int row = flat / 36, idx = flat - row * 36;
        short v = relq[((size_t)bh * NPADK + q0 + row) * 36 + idx];
        lds_write1x(Qse, row, 64 + idx, v);
    }
    if (tid < 64) lds_write1x(Qse, tid, 100, (short)0x3F80);   // 1.0 bf16
    __syncthreads();

    // ---- hoist Q' B-frags ----
    short8v bq[4];
    #pragma unroll
    for (int ks = 0; ks < 4; ks++)
        bq[ks] = lds_read8x(Qse, wid * 16 + larow, ks * 64 + lgrp * 16);

    float m_ = -1e30f, l_ = 0.f;
    f32x4 O4[4];
    #pragma unroll
    for (int nf = 0; nf < 4; nf++) O4[nf] = (f32x4){0.f, 0.f, 0.f, 0.f};

    const int prow = wid * 16 + larow;

    for (int kt = 0; kt < NKT; kt++) {
        __syncthreads();
        // ---- stage via gload_lds from pre-swizzled sources ----
        {
            const int kb0 = kt * 64;
            #pragma unroll
            for (int p = 0; p < 2; p++) {
                const int row = p * 32 + g32row;
                GLOAD_LDS16(kswz + ((size_t)bh * NPADK + kb0 + row) * HD_ + g32col,
                            Kk + p * 2048 + tid * 8);
                GLOAD_LDS16(oneh + (size_t)(kb0 + row) * 64 + g32col,
                            Ke + p * 2048 + tid * 8);
                GLOAD_LDS16(vtb + ((size_t)bh * HD_ + row) * NPADK + kb0 + g32col,
                            VT + p * 2048 + tid * 8);
            }
        }
        __syncthreads();   // drains vmcnt

        // ---- S^T = K' Q'^T via MFMA (bias+mask folded) ----
        f32x4 s4[4];
        #pragma unroll
        for (int nf = 0; nf < 4; nf++) {
            short8v ak[4];
            ak[0] = lds_read8(Kk, nf * 16 + larow, lgrp * 16);
            ak[1] = lds_read8(Kk, nf * 16 + larow, 64 + lgrp * 16);
            ak[2] = lds_read8(Ke, nf * 16 + larow, lgrp * 16);
            ak[3] = lds_read8(Ke, nf * 16 + larow, 64 + lgrp * 16);
            f32x4 acc = (f32x4){0.f, 0.f, 0.f, 0.f};
            #pragma unroll
            for (int ks = 0; ks < 4; ks++)
                acc = __builtin_amdgcn_mfma_f32_16x16x32_bf16(ak[ks], bq[ks], acc, 0, 0, 0);
            s4[nf] = acc;
        }

        // ---- in-lane online softmax with T13 defer-max (THR=8) ----
        float rm = -1e30f;
        #pragma unroll
        for (int nf = 0; nf < 4; nf++)
            #pragma unroll
            for (int r = 0; r < 4; r++) rm = fmaxf(rm, s4[nf][r]);
        rm = fmaxf(rm, __shfl_xor(rm, 16));
        rm = fmaxf(rm, __shfl_xor(rm, 32));
        const bool noresc = __all(rm <= m_ + 8.f);
        float fac = 1.f;
        if (!noresc) {
            float mn = fmaxf(m_, rm);
            fac = __expf(m_ - mn);
            m_ = mn;
        }
        float p[4][4];
        float ps = 0.f;
        #pragma unroll
        for (int nf = 0; nf < 4; nf++)
            #pragma unroll
            for (int r = 0; r < 4; r++) {
                float e = __expf(s4[nf][r] - m_);
                p[nf][r] = e; ps += e;
            }
        ps += __shfl_xor(ps, 16);
        ps += __shfl_xor(ps, 32);
        l_ = l_ * fac + ps;

        #pragma unroll
        for (int nf = 0; nf < 4; nf++)
            lds_writeP(Ps, prow, nf * 32 + lgrp * 8,
                       pk2bf(p[nf][0], p[nf][1]), pk2bf(p[nf][2], p[nf][3]));

        if (!noresc) {
            float facr[4];
            #pragma unroll
            for (int r = 0; r < 4; r++) facr[r] = __shfl(fac, lgrp * 4 + r);
            #pragma unroll
            for (int nf = 0; nf < 4; nf++)
                #pragma unroll
                for (int r = 0; r < 4; r++) O4[nf][r] *= facr[r];
        }

        short8v ap[2];
        ap[0] = lds_read8(Ps, prow, lgrp * 16);
        ap[1] = lds_read8(Ps, prow, 64 + lgrp * 16);
        #pragma unroll
        for (int nf = 0; nf < 4; nf++) {
            #pragma unroll
            for (int ks = 0; ks < 2; ks++) {
                short8v bv2 = lds_read8(VT, nf * 16 + larow, ks * 64 + lgrp * 16);
                O4[nf] = __builtin_amdgcn_mfma_f32_16x16x32_bf16(ap[ks], bv2, O4[nf], 0, 0, 0);
            }
        }
    }

    // ---- finalize: /l, +residual (f32 q), store bf16 ----
    float linv[4];
    #pragma unroll
    for (int r = 0; r < 4; r++) linv[r] = 1.f / __shfl(l_, lgrp * 4 + r);
    #pragma unroll
    for (int nf = 0; nf < 4; nf++) {
        const int d = nf * 16 + larow;
        #pragma unroll
        for (int r = 0; r < 4; r++) {
            const int rowL = wid * 16 + lgrp * 4 + r;
            const int qi = q0 + rowL;
            if (qi < N_) {
                float o = O4[nf][r] * linv[r];
                if (qi > 0) o += pqf[base + (size_t)qi * HD_ + d];
                aoutbf[(size_t)(b * N_ + qi) * (HEADS_ * HD_) + h * HD_ + d] = f2bfs(o);
            }
        }
    }
}

extern "C" void kernel_launch(void* const* d_in, const int* in_sizes, int n_in,
                              void* d_out, int out_size, void* d_ws, size_t ws_size,
                              hipStream_t stream) {
    const float* x    = (const float*)d_in[0];
    const float* Wqkv = (const float*)d_in[1];
    const float* bqkv = (const float*)d_in[2];
    const float* kq   = (const float*)d_in[3];
    const float* kk   = (const float*)d_in[4];
    const float* kv   = (const float*)d_in[5];
    const float* nqw  = (const float*)d_in[6];
    const float* nqb  = (const float*)d_in[7];
    const float* nkw  = (const float*)d_in[8];
    const float* nkb  = (const float*)d_in[9];
    const float* nvw  = (const float*)d_in[10];
    const float* nvb  = (const float*)d_in[11];
    const float* rpt  = (const float*)d_in[12];
    const float* rph  = (const float*)d_in[13];
    const float* rpw  = (const float*)d_in[14];
    const float* Wproj= (const float*)d_in[15];
    const float* bproj= (const float*)d_in[16];
    float* out = (float*)d_out;

    const size_t qkv_elems  = (size_t)M_ * QKVD;
    const size_t pool_elems = (size_t)B_ * HEADS_ * N_ * HD_;
    const size_t kswz_elems = (size_t)B_ * HEADS_ * NPADK * HD_;
    short* qkvb = (short*)d_ws;                    // 28.9 MB
    float* pqf  = (float*)(qkvb + qkv_elems);      // 19.3 MB
    short* qbb  = (short*)(pqf + pool_elems);      // 9.6 MB
    short* kswz = qbb + pool_elems;                // 9.8 MB
    short* abuf = kswz + kswz_elems;               // 9.8 MB (x-bf16, then attn out)
    short* w1t  = abuf + (size_t)MPAD * IND;       // 3.5 MB
    short* vtb  = w1t + (size_t)QKVD * IND;        // 9.8 MB (V^T pre-swizzled)
    short* oneh = vtb + (size_t)B_ * HEADS_ * HD_ * NPADK;  // 0.2 MB (pre-swizzled)
    short* relq = oneh + (size_t)NPADK * 64;       // [48][1600][36] bf16 = 5.5 MB
                                                   // total ~96 MB

    f32_to_bf16_rows<<<MPAD, 256, 0, stream>>>(x, abuf, M_, IND);
    transpose_f32_bf16<<<dim3(QKVD / 32, IND / 32), 256, 0, stream>>>(Wqkv, w1t, IND, QKVD);
    build_onehot<<<NPADK, 64, 0, stream>>>(oneh);

    gemm_mfma<short><<<dim3(QKVD / 128, MPAD / 128), 256, 0, stream>>>(abuf, w1t, bqkv, qkvb, M_, QKVD, IND);

    pool_ln<<<PBLK, 256, 0, stream>>>(qkvb, kq, kk, kv,
        nqw, nqb, nkw, nkb, nvw, nvb, pqf, qbb, kswz, vtb);

    build_relq<<<ABLK, 256, 0, stream>>>(pqf, rpt, rph, rpw, relq);

    attn_mfma<<<ABLK, 256, 0, stream>>>(qbb, kswz, vtb, oneh, relq, pqf, abuf);

    transpose_f32_bf16<<<dim3(IND / 32, IND / 32), 256, 0, stream>>>(Wproj, w1t, IND, IND);
    gemm_mfma<float><<<dim3(IND / 128, MPAD / 128), 256, 0, stream>>>(abuf, w1t, bproj, out, M_, IND, IND);
}

// Round 20
// 309.388 us; speedup vs baseline: 1.4763x; 1.1010x over previous
//
#include <hip/hip_runtime.h>
#include <hip/hip_bf16.h>

#define B_ 4
#define N_ 1569
#define IND 768
#define HEADS_ 12
#define HD_ 64
#define T0_ 8
#define H0_ 14
#define W0_ 14
#define M_ (B_*N_)          // 6276
#define MPAD 6400           // 50*128
#define QKVD (3*IND)        // 2304
#define NKT 25              // key/query tiles of 64
#define NPADK 1600          // padded key count
#define PBLK (3*B_*HEADS_*T0_)   // 1152 pool blocks
#define ABLK (B_*HEADS_*NKT)     // 1200 attn blocks

typedef __attribute__((ext_vector_type(8))) short short8v;
typedef __attribute__((ext_vector_type(8))) float float8;
typedef __attribute__((ext_vector_type(4))) float f32x4;

// async global->LDS 16B
#define GLOAD_LDS16(gp, lp) \
    __builtin_amdgcn_global_load_lds( \
        (const __attribute__((address_space(1))) void*)(gp), \
        (__attribute__((address_space(3))) void*)(lp), 16, 0, 0)

__device__ __forceinline__ short f2bfs(float f) {
    __hip_bfloat16 h = __float2bfloat16(f);
    return *reinterpret_cast<short*>(&h);
}
__device__ __forceinline__ unsigned int pk2bf(float a, float b) {
    return ((unsigned int)(unsigned short)f2bfs(b) << 16) | (unsigned short)f2bfs(a);
}
__device__ __forceinline__ float bfu2f_lo(unsigned int u) {
    union { unsigned int i; float f; } x; x.i = u << 16; return x.f;
}
__device__ __forceinline__ float bfu2f_hi(unsigned int u) {
    union { unsigned int i; float f; } x; x.i = u & 0xFFFF0000u; return x.f;
}

// ---- swizzled LDS helpers: 128B rows ----
__device__ __forceinline__ short8v lds_read8(const short* base, int row, int bir) {
    int byte = row * 128 + (bir ^ ((row & 7) << 4));
    return *reinterpret_cast<const short8v*>(reinterpret_cast<const char*>(base) + byte);
}
__device__ __forceinline__ void lds_writeP(short* base, int row, int bir, unsigned int lo, unsigned int hi) {
    int byte = row * 128 + (bir ^ ((row & 7) << 4));
    uint2 v; v.x = lo; v.y = hi;
    *reinterpret_cast<uint2*>(reinterpret_cast<char*>(base) + byte) = v;
}
// ---- swizzled LDS helpers: 256B rows (Q ext prologue tile) ----
__device__ __forceinline__ short8v lds_read8x(const short* base, int row, int bir) {
    int byte = row * 256 + (bir ^ ((row & 7) << 4));
    return *reinterpret_cast<const short8v*>(reinterpret_cast<const char*>(base) + byte);
}
__device__ __forceinline__ void lds_write8x(short* base, int row, int bir, short8v v) {
    int byte = row * 256 + (bir ^ ((row & 7) << 4));
    *reinterpret_cast<short8v*>(reinterpret_cast<char*>(base) + byte) = v;
}
__device__ __forceinline__ void lds_write1x(short* base, int row, int col, short v) {
    int byte = row * 256 + ((col * 2) ^ ((row & 7) << 4));
    *reinterpret_cast<short*>(reinterpret_cast<char*>(base) + byte) = v;
}

// ---------------- f32 -> bf16 row-wise convert with zero row padding ----------------
__global__ __launch_bounds__(256) void f32_to_bf16_rows(
        const float* __restrict__ src, short* __restrict__ dst, int rows, int cols) {
    const int r = blockIdx.x;
    const bool live = r < rows;
    for (int c = threadIdx.x; c < cols; c += 256) {
        float v = live ? src[(size_t)r * cols + c] : 0.f;
        dst[(size_t)r * cols + c] = f2bfs(v);
    }
}

// ---------------- W[K][N] f32 -> WT[N][K] bf16 ----------------
__global__ __launch_bounds__(256) void transpose_f32_bf16(
        const float* __restrict__ W, short* __restrict__ WT, int K, int N) {
    __shared__ float t[32][33];
    const int n0 = blockIdx.x * 32, k0 = blockIdx.y * 32;
    const int tx = threadIdx.x & 31, ty = threadIdx.x >> 5;
    #pragma unroll
    for (int p = 0; p < 4; p++)
        t[ty + 8 * p][tx] = W[(size_t)(k0 + ty + 8 * p) * N + n0 + tx];
    __syncthreads();
    #pragma unroll
    for (int p = 0; p < 4; p++)
        WT[(size_t)(n0 + ty + 8 * p) * K + k0 + tx] = f2bfs(t[tx][ty + 8 * p]);
}

// ---------------- rel-pos onehot table [NPADK][64] bf16, PRE-SWIZZLED cols ----------------
__global__ __launch_bounds__(64) void build_onehot(short* __restrict__ oneh) {
    const int kg = blockIdx.x;
    const int c = threadIdx.x;
    float v = 0.f;
    if (kg >= N_) {
        if (c == 36) v = -1e30f;
    } else if (kg >= 1) {
        int m = kg - 1;
        int tj = m / 196, rr = m - tj * 196;
        int hj = rr / 14, wj = rr - hj * 14;
        if (c == tj || c == 8 + hj || c == 22 + wj) v = 1.f;
    }
    oneh[(size_t)kg * 64 + (c ^ ((kg & 7) << 3))] = f2bfs(v);
}

// ---------------- precompute rel-pos dots: relq[bh][NPADK rows][36] bf16 ----------------
__global__ __launch_bounds__(256) void build_relq(
        const float* __restrict__ pqf,
        const float* __restrict__ rpt, const float* __restrict__ rph,
        const float* __restrict__ rpw, short* __restrict__ relq) {
    int bid = blockIdx.x;                  // 48*25
    const int qt = bid % NKT; bid /= NKT;
    const int bh = bid;
    const int row = threadIdx.x >> 2, part = threadIdx.x & 3;
    const int qi = qt * 64 + row;
    const bool valid = (qi >= 1 && qi < N_);
    const int m = valid ? (qi - 1) : 0;
    const int ti = m / 196, rr = m - ti * 196;
    const int hi = rr / 14, wi = rr - hi * 14;

    float4 qv[4];
    if (valid) {
        const float4* qp = (const float4*)(pqf + ((size_t)bh * N_ + qi) * HD_ + part * 16);
        qv[0] = qp[0]; qv[1] = qp[1]; qv[2] = qp[2]; qv[3] = qp[3];
    } else {
        #pragma unroll
        for (int j = 0; j < 4; j++) qv[j] = make_float4(0.f, 0.f, 0.f, 0.f);
    }

    short* dst = relq + ((size_t)bh * NPADK + qt * 64 + row) * 36;
    #pragma unroll 4
    for (int idx = 0; idx < 36; idx++) {
        const float* tab;
        if (idx < 8)       tab = rpt + (size_t)(ti - idx + 7) * HD_;
        else if (idx < 22) tab = rph + (size_t)(hi - (idx - 8) + 13) * HD_;
        else               tab = rpw + (size_t)(wi - (idx - 22) + 13) * HD_;
        const float4* tp = (const float4*)(tab + part * 16);
        float acc = 0.f;
        #pragma unroll
        for (int j = 0; j < 4; j++) {
            float4 t = tp[j];
            acc += qv[j].x * t.x + qv[j].y * t.y + qv[j].z * t.z + qv[j].w * t.w;
        }
        acc += __shfl_xor(acc, 1);
        acc += __shfl_xor(acc, 2);
        if (part == 0) dst[idx] = valid ? f2bfs(acc) : (short)0;
    }
}

// ---------------- MFMA GEMM: C[M,N] = A[Mpad,K](bf16) * BT[N,K]^T + bias ----------------
template<typename TOUT>
__global__ __launch_bounds__(256) void gemm_mfma(
        const short* __restrict__ A, const short* __restrict__ BT,
        const float* __restrict__ bias, TOUT* __restrict__ C,
        int M, int N, int K) {
    __shared__ __align__(16) short As[128 * 32];
    __shared__ __align__(16) short Bs[128 * 32];
    const int tid = threadIdx.x;
    const int lane = tid & 63;
    const int wid = tid >> 6;
    const int bm = blockIdx.y * 128;
    const int bn = blockIdx.x * 128;
    const int wr = (wid >> 1) * 64, wc = (wid & 1) * 64;
    const int larow = lane & 15, lak = (lane >> 4) * 8;
    const int srow = tid >> 2, sk = (tid & 3) * 8;

    f32x4 acc[4][4];
    #pragma unroll
    for (int m = 0; m < 4; m++)
        #pragma unroll
        for (int n = 0; n < 4; n++) acc[m][n] = (f32x4){0.f, 0.f, 0.f, 0.f};

    for (int kt = 0; kt < K; kt += 32) {
        __syncthreads();
        GLOAD_LDS16(A  + (size_t)(bm + srow) * K + kt + sk,       As + srow * 32 + sk);
        GLOAD_LDS16(A  + (size_t)(bm + 64 + srow) * K + kt + sk,  As + (64 + srow) * 32 + sk);
        GLOAD_LDS16(BT + (size_t)(bn + srow) * K + kt + sk,       Bs + srow * 32 + sk);
        GLOAD_LDS16(BT + (size_t)(bn + 64 + srow) * K + kt + sk,  Bs + (64 + srow) * 32 + sk);
        __syncthreads();

        short8v af[4], bfv[4];
        #pragma unroll
        for (int m = 0; m < 4; m++)
            af[m] = *(const short8v*)&As[(wr + m * 16 + larow) * 32 + lak];
        #pragma unroll
        for (int n = 0; n < 4; n++)
            bfv[n] = *(const short8v*)&Bs[(wc + n * 16 + larow) * 32 + lak];
        __builtin_amdgcn_s_setprio(1);
        #pragma unroll
        for (int m = 0; m < 4; m++)
            #pragma unroll
            for (int n = 0; n < 4; n++)
                acc[m][n] = __builtin_amdgcn_mfma_f32_16x16x32_bf16(af[m], bfv[n], acc[m][n], 0, 0, 0);
        __builtin_amdgcn_s_setprio(0);
    }

    const int crow = (lane >> 4) * 4;
    const int ccol = lane & 15;
    #pragma unroll
    for (int n = 0; n < 4; n++) {
        const int col = bn + wc + n * 16 + ccol;
        const float bv = bias[col];
        #pragma unroll
        for (int m = 0; m < 4; m++) {
            #pragma unroll
            for (int r2 = 0; r2 < 4; r2++) {
                const int row = bm + wr + m * 16 + crow + r2;
                if (row < M) {
                    float v = acc[m][n][r2] + bv;
                    if constexpr (sizeof(TOUT) == 2) C[(size_t)row * N + col] = f2bfs(v);
                    else                             C[(size_t)row * N + col] = v;
                }
            }
        }
    }
}

// ---------------- LDS-staged depthwise 3x3x3 conv pool + LayerNorm(64) ----------------
// 512 threads = 8 waves (2 blocks/CU -> 16 waves/CU; was 8). Same 73.5KB LDS.
// K -> kswz [bh][NPADK][64] col ^ ((n&7)<<3); V -> vtb [bh][d][NPADK] per-64-tile col ^ ((d&7)<<3).
__global__ __launch_bounds__(512) void pool_ln(
        const short* __restrict__ qkvb,
        const float* __restrict__ kq, const float* __restrict__ kk,
        const float* __restrict__ kv,
        const float* __restrict__ nqw, const float* __restrict__ nqb,
        const float* __restrict__ nkw, const float* __restrict__ nkb,
        const float* __restrict__ nvw, const float* __restrict__ nvb,
        float* __restrict__ pqf, short* __restrict__ qbb,
        short* __restrict__ kswz, short* __restrict__ vtb) {
    __shared__ __align__(16) short sp[3 * 196 * 64];

    const int tid = threadIdx.x;
    const int lane = tid & 63;
    const int wid = tid >> 6;          // 0..7
    const int li = lane & 31;
    const int halfB = lane >> 5;

    int bid = (blockIdx.x & 7) * (PBLK / 8) + (blockIdx.x >> 3);
    const int t = bid & 7; bid >>= 3;
    const int head = bid % HEADS_; bid /= HEADS_;
    const int b = bid % B_;
    const int s = bid / B_;

    const float* kern = (s == 0) ? kq : ((s == 1) ? kk : kv);
    const float* lw = (s == 0) ? nqw : ((s == 1) ? nkw : nvw);
    const float* lb = (s == 0) ? nqb : ((s == 1) ? nkb : nvb);

    float kwA[27], kwB[27];
    #pragma unroll
    for (int i = 0; i < 27; i++) {
        kwA[i] = kern[(2 * li) * 27 + i];
        kwB[i] = kern[(2 * li + 1) * 27 + i];
    }
    const float lw0 = lw[2 * li], lw1 = lw[2 * li + 1];
    const float lb0 = lb[2 * li], lb1 = lb[2 * li + 1];
    const float oscale = (s == 0) ? 0.125f : 1.f;

    const int colbase = s * IND + head * HD_;

    for (int c = tid; c < 3 * 196 * 8; c += 512) {
        const int p = c / 1568, rem = c - p * 1568;
        const int t2 = t - 1 + p;
        short8v v = {0,0,0,0,0,0,0,0};
        if (t2 >= 0 && t2 < T0_) {
            const int node = rem >> 3, seg = rem & 7;
            v = *(const short8v*)(qkvb +
                (size_t)(b * N_ + 1 + t2 * 196 + node) * QKVD + colbase + seg * 8);
        }
        *(short8v*)&sp[c * 8] = v;
    }
    __syncthreads();

    const int bh = b * HEADS_ + head;
    const size_t qbase  = (size_t)bh * N_ * HD_ + 2 * li;
    const size_t kbase  = (size_t)bh * NPADK * HD_;
    const size_t vtbase = (size_t)bh * HD_ * NPADK;

    for (int pr = wid; pr < 98; pr += 8) {
        const int node = pr * 2 + halfB;
        const int hi = node / 14, wi = node - hi * 14;
        float y0 = 0.f, y1 = 0.f;
        #pragma unroll
        for (int kt2 = 0; kt2 < 3; kt2++)
            #pragma unroll
            for (int kh = 0; kh < 3; kh++)
                #pragma unroll
                for (int kw_ = 0; kw_ < 3; kw_++) {
                    const int h2 = hi + kh - 1, w2 = wi + kw_ - 1;
                    const bool ok = ((unsigned)h2 < 14u) && ((unsigned)w2 < 14u);
                    const int n2 = ok ? (h2 * 14 + w2) : 0;
                    const unsigned int u =
                        *(const unsigned int*)&sp[(kt2 * 196 + n2) * 64 + 2 * li];
                    const int ki = (kt2 * 3 + kh) * 3 + kw_;
                    const float w0 = ok ? kwA[ki] : 0.f;
                    const float w1 = ok ? kwB[ki] : 0.f;
                    y0 += bfu2f_lo(u) * w0;
                    y1 += bfu2f_hi(u) * w1;
                }
        float s1 = y0 + y1;
        #pragma unroll
        for (int o = 16; o > 0; o >>= 1) s1 += __shfl_xor(s1, o);
        const float mu = s1 * (1.f / 64.f);
        const float d0 = y0 - mu, d1 = y1 - mu;
        float s2 = d0 * d0 + d1 * d1;
        #pragma unroll
        for (int o = 16; o > 0; o >>= 1) s2 += __shfl_xor(s2, o);
        const float inv = rsqrtf(s2 * (1.f / 64.f) + 1e-5f);
        const float o0 = d0 * inv * lw0 + lb0;
        const float o1 = d1 * inv * lw1 + lb1;

        const int n = 1 + t * 196 + node;
        if (s == 2) {
            const int base64 = n & ~63, loc = n & 63;
            vtb[vtbase + (size_t)(2 * li) * NPADK + base64 + (loc ^ (((2 * li) & 7) << 3))]         = f2bfs(o0);
            vtb[vtbase + (size_t)(2 * li + 1) * NPADK + base64 + (loc ^ (((2 * li + 1) & 7) << 3))] = f2bfs(o1);
        } else if (s == 1) {
            const int cswz = (2 * li) ^ ((n & 7) << 3);
            *(unsigned int*)&kswz[kbase + (size_t)n * HD_ + cswz] = pk2bf(o0, o1);
        } else {
            const size_t idx = qbase + (size_t)n * HD_;
            *(unsigned int*)&qbb[idx] = pk2bf(o0 * oscale, o1 * oscale);
            float2 f2; f2.x = o0; f2.y = o1;
            *(float2*)&pqf[idx] = f2;
        }
    }

    if (t == 0 && wid == 0) {
        const unsigned int u =
            *(const unsigned int*)(qkvb + (size_t)(b * N_) * QKVD + colbase + 2 * li);
        const float y0 = bfu2f_lo(u), y1 = bfu2f_hi(u);
        float s1 = y0 + y1;
        #pragma unroll
        for (int o = 16; o > 0; o >>= 1) s1 += __shfl_xor(s1, o);
        const float mu = s1 * (1.f / 64.f);
        const float d0 = y0 - mu, d1 = y1 - mu;
        float s2 = d0 * d0 + d1 * d1;
        #pragma unroll
        for (int o = 16; o > 0; o >>= 1) s2 += __shfl_xor(s2, o);
        const float inv = rsqrtf(s2 * (1.f / 64.f) + 1e-5f);
        const float o0 = d0 * inv * lw0 + lb0;
        const float o1 = d1 * inv * lw1 + lb1;
        if (halfB == 0) {
            if (s == 2) {
                vtb[vtbase + (size_t)(2 * li) * NPADK + (((2 * li) & 7) << 3)]         = f2bfs(o0);
                vtb[vtbase + (size_t)(2 * li + 1) * NPADK + (((2 * li + 1) & 7) << 3)] = f2bfs(o1);
            } else if (s == 1) {
                *(unsigned int*)&kswz[kbase + 2 * li] = pk2bf(o0, o1);
            } else {
                *(unsigned int*)&qbb[qbase] = pk2bf(o0 * oscale, o1 * oscale);
                float2 f2; f2.x = o0; f2.y = o1;
                *(float2*)&pqf[qbase] = f2;
            }
        }
    }
}

// ---------------- MFMA flash attention: precomputed relq; gload_lds staging ----------------
// LDS 32KB: Kk[64][128B] | Ke[64][128B] | VT[64][128B] | Ps[64][128B]; Qse(16KB) overlays Kk+Ke.
__global__ __launch_bounds__(256) void attn_mfma(
        const short* __restrict__ qb, const short* __restrict__ kswz,
        const short* __restrict__ vtb, const short* __restrict__ oneh,
        const short* __restrict__ relq, const float* __restrict__ pqf,
        short* __restrict__ aoutbf) {
    __shared__ __align__(16) short LDSbuf[16384];   // 32 KB

    short* Qse = LDSbuf;            // prologue only (16KB, 256B rows)
    short* Kk  = LDSbuf;            // 8KB, 128B rows
    short* Ke  = LDSbuf + 4096;     // 8KB, 128B rows
    short* VT  = LDSbuf + 8192;     // 8KB, 128B rows
    short* Ps  = LDSbuf + 12288;    // 8KB, 128B rows

    const int tid = threadIdx.x;
    const int lane = tid & 63;
    const int wid = tid >> 6;
    const int larow = lane & 15;
    const int lgrp = lane >> 4;

    int bid = (blockIdx.x & 7) * (ABLK / 8) + (blockIdx.x >> 3);
    const int qt = bid % NKT; bid /= NKT;
    const int h = bid % HEADS_;
    const int b = bid / HEADS_;
    const int q0 = qt * 64;
    const int bh = b * HEADS_ + h;
    const size_t base = (size_t)bh * N_ * HD_;

    const int g32row = tid >> 3;
    const int g32col = (tid & 7) * 8;

    // ---- prologue: stage Qext (zero-padded; ext half zeroed) ----
    {
        const int row = tid >> 2, seg = tid & 3;
        const int qi = q0 + row;
        short8v v0 = {0,0,0,0,0,0,0,0}, v1 = v0, z = v0;
        if (qi < N_) {
            const short8v* g = (const short8v*)(qb + base + (size_t)qi * HD_ + seg * 16);
            v0 = g[0]; v1 = g[1];
        }
        lds_write8x(Qse, row, seg * 32, v0);
        lds_write8x(Qse, row, seg * 32 + 16, v1);
        lds_write8x(Qse, row, 128 + seg * 32, z);
        lds_write8x(Qse, row, 128 + seg * 32 + 16, z);
    }
    __syncthreads();

    // ---- copy precomputed rel dots -> Qext cols 64..99; mask col 100 = 1.0 ----
    #pragma unroll
    for (int it = 0; it < 9; it++) {           // 9*256 = 2304 = 64*36
        int flat = it * 256 + tid;
        int row = flat / 36, idx = flat - row * 36;
        short v = relq[((size_t)bh * NPADK + q0 + row) * 36 + idx];
        lds_write1x(Qse, row, 64 + idx, v);
    }
    if (tid < 64) lds_write1x(Qse, tid, 100, (short)0x3F80);   // 1.0 bf16
    __syncthreads();

    // ---- hoist Q' B-frags ----
    short8v bq[4];
    #pragma unroll
    for (int ks = 0; ks < 4; ks++)
        bq[ks] = lds_read8x(Qse, wid * 16 + larow, ks * 64 + lgrp * 16);

    float m_ = -1e30f, l_ = 0.f;
    f32x4 O4[4];
    #pragma unroll
    for (int nf = 0; nf < 4; nf++) O4[nf] = (f32x4){0.f, 0.f, 0.f, 0.f};

    const int prow = wid * 16 + larow;

    for (int kt = 0; kt < NKT; kt++) {
        __syncthreads();
        // ---- stage via gload_lds from pre-swizzled sources ----
        {
            const int kb0 = kt * 64;
            #pragma unroll
            for (int p = 0; p < 2; p++) {
                const int row = p * 32 + g32row;
                GLOAD_LDS16(kswz + ((size_t)bh * NPADK + kb0 + row) * HD_ + g32col,
                            Kk + p * 2048 + tid * 8);
                GLOAD_LDS16(oneh + (size_t)(kb0 + row) * 64 + g32col,
                            Ke + p * 2048 + tid * 8);
                GLOAD_LDS16(vtb + ((size_t)bh * HD_ + row) * NPADK + kb0 + g32col,
                            VT + p * 2048 + tid * 8);
            }
        }
        __syncthreads();   // drains vmcnt

        // ---- S^T = K' Q'^T via MFMA (bias+mask folded) ----
        f32x4 s4[4];
        #pragma unroll
        for (int nf = 0; nf < 4; nf++) {
            short8v ak[4];
            ak[0] = lds_read8(Kk, nf * 16 + larow, lgrp * 16);
            ak[1] = lds_read8(Kk, nf * 16 + larow, 64 + lgrp * 16);
            ak[2] = lds_read8(Ke, nf * 16 + larow, lgrp * 16);
            ak[3] = lds_read8(Ke, nf * 16 + larow, 64 + lgrp * 16);
            f32x4 acc = (f32x4){0.f, 0.f, 0.f, 0.f};
            #pragma unroll
            for (int ks = 0; ks < 4; ks++)
                acc = __builtin_amdgcn_mfma_f32_16x16x32_bf16(ak[ks], bq[ks], acc, 0, 0, 0);
            s4[nf] = acc;
        }

        // ---- in-lane online softmax with T13 defer-max (THR=8) ----
        float rm = -1e30f;
        #pragma unroll
        for (int nf = 0; nf < 4; nf++)
            #pragma unroll
            for (int r = 0; r < 4; r++) rm = fmaxf(rm, s4[nf][r]);
        rm = fmaxf(rm, __shfl_xor(rm, 16));
        rm = fmaxf(rm, __shfl_xor(rm, 32));
        const bool noresc = __all(rm <= m_ + 8.f);
        float fac = 1.f;
        if (!noresc) {
            float mn = fmaxf(m_, rm);
            fac = __expf(m_ - mn);
            m_ = mn;
        }
        float p[4][4];
        float ps = 0.f;
        #pragma unroll
        for (int nf = 0; nf < 4; nf++)
            #pragma unroll
            for (int r = 0; r < 4; r++) {
                float e = __expf(s4[nf][r] - m_);
                p[nf][r] = e; ps += e;
            }
        ps += __shfl_xor(ps, 16);
        ps += __shfl_xor(ps, 32);
        l_ = l_ * fac + ps;

        #pragma unroll
        for (int nf = 0; nf < 4; nf++)
            lds_writeP(Ps, prow, nf * 32 + lgrp * 8,
                       pk2bf(p[nf][0], p[nf][1]), pk2bf(p[nf][2], p[nf][3]));

        if (!noresc) {
            float facr[4];
            #pragma unroll
            for (int r = 0; r < 4; r++) facr[r] = __shfl(fac, lgrp * 4 + r);
            #pragma unroll
            for (int nf = 0; nf < 4; nf++)
                #pragma unroll
                for (int r = 0; r < 4; r++) O4[nf][r] *= facr[r];
        }

        short8v ap[2];
        ap[0] = lds_read8(Ps, prow, lgrp * 16);
        ap[1] = lds_read8(Ps, prow, 64 + lgrp * 16);
        #pragma unroll
        for (int nf = 0; nf < 4; nf++) {
            #pragma unroll
            for (int ks = 0; ks < 2; ks++) {
                short8v bv2 = lds_read8(VT, nf * 16 + larow, ks * 64 + lgrp * 16);
                O4[nf] = __builtin_amdgcn_mfma_f32_16x16x32_bf16(ap[ks], bv2, O4[nf], 0, 0, 0);
            }
        }
    }

    // ---- finalize: /l, +residual (f32 q), store bf16 ----
    float linv[4];
    #pragma unroll
    for (int r = 0; r < 4; r++) linv[r] = 1.f / __shfl(l_, lgrp * 4 + r);
    #pragma unroll
    for (int nf = 0; nf < 4; nf++) {
        const int d = nf * 16 + larow;
        #pragma unroll
        for (int r = 0; r < 4; r++) {
            const int rowL = wid * 16 + lgrp * 4 + r;
            const int qi = q0 + rowL;
            if (qi < N_) {
                float o = O4[nf][r] * linv[r];
                if (qi > 0) o += pqf[base + (size_t)qi * HD_ + d];
                aoutbf[(size_t)(b * N_ + qi) * (HEADS_ * HD_) + h * HD_ + d] = f2bfs(o);
            }
        }
    }
}

extern "C" void kernel_launch(void* const* d_in, const int* in_sizes, int n_in,
                              void* d_out, int out_size, void* d_ws, size_t ws_size,
                              hipStream_t stream) {
    const float* x    = (const float*)d_in[0];
    const float* Wqkv = (const float*)d_in[1];
    const float* bqkv = (const float*)d_in[2];
    const float* kq   = (const float*)d_in[3];
    const float* kk   = (const float*)d_in[4];
    const float* kv   = (const float*)d_in[5];
    const float* nqw  = (const float*)d_in[6];
    const float* nqb  = (const float*)d_in[7];
    const float* nkw  = (const float*)d_in[8];
    const float* nkb  = (const float*)d_in[9];
    const float* nvw  = (const float*)d_in[10];
    const float* nvb  = (const float*)d_in[11];
    const float* rpt  = (const float*)d_in[12];
    const float* rph  = (const float*)d_in[13];
    const float* rpw  = (const float*)d_in[14];
    const float* Wproj= (const float*)d_in[15];
    const float* bproj= (const float*)d_in[16];
    float* out = (float*)d_out;

    const size_t qkv_elems  = (size_t)M_ * QKVD;
    const size_t pool_elems = (size_t)B_ * HEADS_ * N_ * HD_;
    const size_t kswz_elems = (size_t)B_ * HEADS_ * NPADK * HD_;
    short* qkvb = (short*)d_ws;                    // 28.9 MB
    float* pqf  = (float*)(qkvb + qkv_elems);      // 19.3 MB
    short* qbb  = (short*)(pqf + pool_elems);      // 9.6 MB
    short* kswz = qbb + pool_elems;                // 9.8 MB
    short* abuf = kswz + kswz_elems;               // 9.8 MB (x-bf16, then attn out)
    short* w1t  = abuf + (size_t)MPAD * IND;       // 3.5 MB
    short* vtb  = w1t + (size_t)QKVD * IND;        // 9.8 MB (V^T pre-swizzled)
    short* oneh = vtb + (size_t)B_ * HEADS_ * HD_ * NPADK;  // 0.2 MB (pre-swizzled)
    short* relq = oneh + (size_t)NPADK * 64;       // [48][1600][36] bf16 = 5.5 MB

    f32_to_bf16_rows<<<MPAD, 256, 0, stream>>>(x, abuf, M_, IND);
    transpose_f32_bf16<<<dim3(QKVD / 32, IND / 32), 256, 0, stream>>>(Wqkv, w1t, IND, QKVD);
    build_onehot<<<NPADK, 64, 0, stream>>>(oneh);

    gemm_mfma<short><<<dim3(QKVD / 128, MPAD / 128), 256, 0, stream>>>(abuf, w1t, bqkv, qkvb, M_, QKVD, IND);

    pool_ln<<<PBLK, 512, 0, stream>>>(qkvb, kq, kk, kv,
        nqw, nqb, nkw, nkb, nvw, nvb, pqf, qbb, kswz, vtb);

    build_relq<<<ABLK, 256, 0, stream>>>(pqf, rpt, rph, rpw, relq);

    attn_mfma<<<ABLK, 256, 0, stream>>>(qbb, kswz, vtb, oneh, relq, pqf, abuf);

    transpose_f32_bf16<<<dim3(IND / 32, IND / 32), 256, 0, stream>>>(Wproj, w1t, IND, IND);
    gemm_mfma<float><<<dim3(IND / 128, MPAD / 128), 256, 0, stream>>>(abuf, w1t, bproj, out, M_, IND, IND);
}